// Round 7
// baseline (3184.606 us; speedup 1.0000x reference)
//
#include <hip/hip_runtime.h>

// V=16000 E=512 H=512 L=2 S=128 T=128 B=64; gate dim 4H=2048
// One fused recurrence kernel, lockstep rounds r=0..255. Layer 0 (WGs 0..31)
// computes step g=r (active r<255); layer 1 (WGs 32..63) computes g=r-1
// (active r>=1). Both layers: K=1024 concat GEMM [x|h]@[Wih|Whh]^T + bias.
// Layer-0 h history = 2-slot ring (parity of state index); layer-1 h history
// = full 257 slots (slot s = state after s steps; 129..255 feed the logits
// GEMM, slot 256 = zero pad). X holds enc (rows 0..8191) + dec (8192..16319)
// embeddings, slot stride 32768 shorts. Weight slices live XOR-swizzled in
// LDS; each WG reloads its dec slice once at its phase switch.
// r7: activation fragments are register-prefetched (32 x v8h, fully unrolled)
// before the MFMA loop -- one global-load latency per round instead of 32.
// WS budget ~65 MB (<=72 MB proven safe; >=140 MB failed = overflow).

typedef __attribute__((ext_vector_type(8))) short v8s;
typedef __attribute__((ext_vector_type(4))) short v4s;
typedef __attribute__((ext_vector_type(8))) _Float16 v8h;
typedef __attribute__((ext_vector_type(4))) float v4f;
typedef __attribute__((ext_vector_type(4))) unsigned int v4u;

#define AS1 __attribute__((address_space(1)))
#define AS3 __attribute__((address_space(3)))

__device__ __forceinline__ short f2h(float x) {
  _Float16 h = (_Float16)x;
  return __builtin_bit_cast(short, h);
}
__device__ __forceinline__ void gload16(const void* g, void* l) {
  __builtin_amdgcn_global_load_lds((const AS1 void*)g, (AS3 void*)l, 16, 0, 0);
}
__device__ __forceinline__ float sigf(float x) { return 1.f / (1.f + __expf(-x)); }
__device__ __forceinline__ float tanhfast(float x) { return 2.f / (1.f + __expf(-2.f * x)) - 1.f; }

// ---------- weight convert fp32->fp16 + gate reorder (i,f,g,o interleave per unit)
__global__ void conv_w(const float* __restrict__ in, short* __restrict__ out,
                       int rows, int ldo, int coloff, int reorder) {
  int i = blockIdx.x * 256 + threadIdx.x;       // one float4 per thread
  if (i >= rows * 128) return;                  // K=512 -> 128 quads per row
  int r = i >> 7, k4 = (i & 127) * 4;
  int rr = reorder ? ((r & 511) * 4 + (r >> 9)) : r;
  float4 v = *(const float4*)(in + (size_t)r * 512 + k4);
  v4s s; s[0] = f2h(v.x); s[1] = f2h(v.y); s[2] = f2h(v.z); s[3] = f2h(v.w);
  *(v4s*)(out + (size_t)rr * ldo + coloff + k4) = s;
}

__global__ void conv_b(const float* __restrict__ a, const float* __restrict__ b,
                       float* __restrict__ o) {
  int r = blockIdx.x * 256 + threadIdx.x;
  if (r < 2048) o[(r & 511) * 4 + (r >> 9)] = a[r] + b[r];
}

// ---------- embedding gather to fp16, rows >= nvalid get zeros
__global__ void embed_k(const int* __restrict__ ids, const float* __restrict__ emb,
                        short* __restrict__ out, int nvalid) {
  int row = blockIdx.x;
  int e = threadIdx.x * 2;
  float2 v = make_float2(0.f, 0.f);
  if (row < nvalid) {
    int id = ids[row];
    v = *(const float2*)(emb + (size_t)id * 512 + e);
  }
  unsigned pack = ((unsigned)(unsigned short)f2h(v.y) << 16) | (unsigned short)f2h(v.x);
  *(unsigned*)(out + (size_t)row * 512 + e) = pack;
}

__global__ void zero_k(short* p, int n) {
  int i = blockIdx.x * 256 + threadIdx.x;
  if (i < n) p[i] = 0;
}

// ---------- GEMM: C[M,N] = A[M,K] * B[N,K]^T (+bias), 128x128 tile, BK=64, fp16
#define GF_BIAS 2
#define GF_GUARDM 4

__global__ __launch_bounds__(256, 2) void gemm_bt(
    const short* __restrict__ Am, const short* __restrict__ Bm,
    const float* __restrict__ bias, float* __restrict__ Cm,
    int M, int N, int K, int ldc, int flags) {
  __shared__ short lA[128 * 64];
  __shared__ short lB[128 * 64];
  const int tid = threadIdx.x, lane = tid & 63, wave = tid >> 6;
  const int wm = wave >> 1, wn = wave & 1;
  const int tm = blockIdx.y, tn = blockIdx.x;
  v4f acc[4][4] = {};
  const short* Abase = Am + (size_t)tm * 128 * K;
  const short* Bbase = Bm + (size_t)tn * 128 * K;

  for (int kt = 0; kt < K; kt += 64) {
    __syncthreads();
#pragma unroll
    for (int i2 = 0; i2 < 4; ++i2) {
      int c = (wave * 4 + i2) * 64 + lane;    // 16B chunk id, 1024 per tile
      int row = c >> 3, ch = c & 7;
      int sch = ch ^ (row & 7);               // inverse swizzle on global source
      gload16(Abase + (size_t)row * K + kt + sch * 8, (char*)lA + (wave * 4 + i2) * 1024);
      gload16(Bbase + (size_t)row * K + kt + sch * 8, (char*)lB + (wave * 4 + i2) * 1024);
    }
    asm volatile("s_waitcnt vmcnt(0)" ::: "memory");
    __syncthreads();
#pragma unroll
    for (int kc = 0; kc < 2; ++kc) {
      v8h af[4], bh[4];
#pragma unroll
      for (int mt = 0; mt < 4; ++mt) {
        int row = wm * 64 + mt * 16 + (lane & 15);
        af[mt] = *(const v8h*)((const char*)lA + row * 128 +
                               ((kc * 64 + (lane >> 4) * 16) ^ ((row & 7) << 4)));
      }
#pragma unroll
      for (int nt = 0; nt < 4; ++nt) {
        int row = wn * 64 + nt * 16 + (lane & 15);
        bh[nt] = *(const v8h*)((const char*)lB + row * 128 +
                               ((kc * 64 + (lane >> 4) * 16) ^ ((row & 7) << 4)));
      }
#pragma unroll
      for (int mt = 0; mt < 4; ++mt)
#pragma unroll
        for (int nt = 0; nt < 4; ++nt)
          acc[mt][nt] = __builtin_amdgcn_mfma_f32_16x16x32_f16(af[mt], bh[nt], acc[mt][nt], 0, 0, 0);
    }
  }

  const int rbase = tm * 128 + wm * 64 + (lane >> 4) * 4;
  const int cbase = tn * 128 + wn * 64 + (lane & 15);
#pragma unroll
  for (int mt = 0; mt < 4; ++mt) {
#pragma unroll
    for (int nt = 0; nt < 4; ++nt) {
      int gc = cbase + nt * 16;
      float bv = (flags & GF_BIAS) ? bias[gc] : 0.f;
#pragma unroll
      for (int rg = 0; rg < 4; ++rg) {
        int gr = rbase + mt * 16 + rg;
        if ((flags & GF_GUARDM) && gr >= M) continue;
        Cm[(size_t)gr * ldc + gc] = acc[mt][nt][rg] + bv;
      }
    }
  }
}

// ---------- fused 2-layer enc+dec LSTM pipeline, lockstep rounds
struct PipeArgs {
  const short* W0e;  // [2048][1024] fp16 [Wih|Whh] gate-reordered, layer0 enc
  const short* W0d;  // layer0 dec
  const short* W1e;  // layer1 enc
  const short* W1d;  // layer1 dec
  const short* X;    // [255 slots][64][512] fp16 embeddings (slot g = x_g)
  const float* b0e;  // [2048] fp32 reordered biases
  const float* b0d;
  const float* b1e;
  const float* b1d;
  short* h0ring;     // 2 slots (state-index parity)
  short* h1;         // 257 slots
  unsigned* flags;   // [64] per-WG round flags
  int Tenc, Ttot;    // 128, 255
};

#define PRE_LD 72
#define SLOT 32768

__global__ __launch_bounds__(256, 1) void lstm_pipe(PipeArgs A) {
  __shared__ __align__(16) short Wlds[64 * 1024];   // 128 KB
  __shared__ __align__(16) float pre[64 * PRE_LD];  // 18 KB
  __shared__ __align__(16) short hsm[64 * 16];      // 2 KB
  const int tid = threadIdx.x, lane = tid & 63, wave = tid >> 6;
  const int w = blockIdx.x, layer = w >> 5, wl = w & 31;

  // stage a [64][1024] weight slice into LDS (XOR swizzle on byte bits 4..6)
  auto stage = [&](const short* Wsrc) {
    for (int i = tid * 8; i < 64 * 1024; i += 256 * 8) {
      int row = i >> 10, k = i & 1023;
      v8s v = *(const v8s*)(Wsrc + (size_t)row * 1024 + k);
      *(v8s*)((char*)Wlds + row * 2048 + ((k * 2) ^ ((row & 7) << 4))) = v;
    }
  };
  stage((layer ? A.W1e : A.W0e) + (size_t)(wl * 64) * 1024);

  const int uu = tid & 15, bq0 = tid >> 4;
  const float* bpe = (layer ? A.b1e : A.b0e) + wl * 64 + uu * 4;
  const float* bpd = (layer ? A.b1d : A.b0d) + wl * 64 + uu * 4;
  const float be0 = bpe[0], be1 = bpe[1], be2 = bpe[2], be3 = bpe[3];
  const float bd0 = bpd[0], bd1 = bpd[1], bd2 = bpd[2], bd3 = bpd[3];
  float creg[4] = {0.f, 0.f, 0.f, 0.f};

  const int arow = wave * 16 + (lane & 15);
  const int koff = (lane >> 4) * 8;
  __syncthreads();

  const int R = A.Ttot + 1;   // 256 rounds
  for (int r = 0; r < R; ++r) {
    // phase-switch weight reloads (WG-uniform conditions)
    if (!layer && r == A.Tenc) {            // layer0 first dec step is g=128=r
      stage(A.W0d + (size_t)(wl * 64) * 1024);
      __syncthreads();
    }
    if (layer && r == A.Tenc + 1) {         // layer1 first dec step at r=129
      stage(A.W1d + (size_t)(wl * 64) * 1024);
      __syncthreads();
    }

    const int g = layer ? (r - 1) : r;
    const bool active = layer ? (r >= 1) : (r < A.Ttot);

    if (active) {
      // K=1024 concat GEMM: gates = [x_or_y0 | h_prev] @ W^T
      // Register-prefetch all 32 activation fragments (one latency, not 32).
      const short* s1 = layer ? (A.h0ring + (size_t)((g + 1) & 1) * SLOT)  // y0[g]
                              : (A.X + (size_t)g * SLOT);                   // x[g]
      const short* s2 = layer ? (A.h1 + (size_t)g * SLOT)                   // h1[g]
                              : (A.h0ring + (size_t)(g & 1) * SLOT);        // h0[g]
      const short* p1 = s1 + (size_t)arow * 512 + koff;
      const short* p2 = s2 + (size_t)arow * 512 + koff;
      v8h af[32];
#pragma unroll
      for (int kc = 0; kc < 16; ++kc) af[kc] = *(const v8h*)(p1 + kc * 32);
#pragma unroll
      for (int kc = 0; kc < 16; ++kc) af[kc + 16] = *(const v8h*)(p2 + kc * 32);
      v4f acc[4] = {};
#pragma unroll
      for (int kc = 0; kc < 32; ++kc) {
        int kg = kc * 32 + koff;
#pragma unroll
        for (int nt = 0; nt < 4; ++nt) {
          int wrow = nt * 16 + (lane & 15);
          v8h bh = *(const v8h*)((const char*)Wlds + wrow * 2048 +
                                 ((kg * 2) ^ ((wrow & 7) << 4)));
          acc[nt] = __builtin_amdgcn_mfma_f32_16x16x32_f16(af[kc], bh, acc[nt], 0, 0, 0);
        }
      }
#pragma unroll
      for (int nt = 0; nt < 4; ++nt)
#pragma unroll
        for (int rg = 0; rg < 4; ++rg)
          pre[(wave * 16 + (lane >> 4) * 4 + rg) * PRE_LD + nt * 16 + (lane & 15)] = acc[nt][rg];
    }
    __syncthreads();
    if (active) {
      const bool enc = g < A.Tenc;
#pragma unroll
      for (int q = 0; q < 4; ++q) {
        int b = q * 16 + bq0;
        v4f gv = *(const v4f*)(&pre[b * PRE_LD + uu * 4]);
        float g0 = gv[0] + (enc ? be0 : bd0);
        float g1 = gv[1] + (enc ? be1 : bd1);
        float g2 = gv[2] + (enc ? be2 : bd2);
        float g3 = gv[3] + (enc ? be3 : bd3);
        float c = sigf(g1) * creg[q] + sigf(g0) * tanhfast(g2);
        creg[q] = c;
        float h = sigf(g3) * tanhfast(c);
        hsm[b * 16 + uu] = f2h(h);
      }
      __syncthreads();
      // publish h state g+1: 16B write-through stores
      if (tid < 128) {
        int b = tid >> 1, half = tid & 1;
        v4u d = *(const v4u*)(&hsm[b * 16 + half * 8]);
        short* dst = (layer ? (A.h1 + (size_t)(g + 1) * SLOT)
                            : (A.h0ring + (size_t)((g + 1) & 1) * SLOT))
                     + b * 512 + wl * 16 + half * 8;
        asm volatile("global_store_dwordx4 %0, %1, off sc1" :: "v"(dst), "v"(d) : "memory");
      }
      asm volatile("s_waitcnt vmcnt(0)" ::: "memory");
    }
    __syncthreads();

    // lockstep barrier (skip after final round)
    if (r < R - 1) {
      if (tid == 0)
        __hip_atomic_store(&A.flags[w], (unsigned)(r + 1), __ATOMIC_RELAXED,
                           __HIP_MEMORY_SCOPE_AGENT);
      if (wave == 0) {
        const unsigned tgt = (unsigned)(r + 1);
        unsigned v;
        do {
          v = __hip_atomic_load(&A.flags[lane], __ATOMIC_RELAXED,
                                __HIP_MEMORY_SCOPE_AGENT);
        } while (!__all((int)(v >= tgt)));
      }
      __syncthreads();
      asm volatile("s_waitcnt vmcnt(0) lgkmcnt(0)\n\tbuffer_inv sc1" ::: "memory");
    }
  }
}

extern "C" void kernel_launch(void* const* d_in, const int* in_sizes, int n_in,
                              void* d_out, int out_size, void* d_ws, size_t ws_size,
                              hipStream_t stream) {
  (void)in_sizes; (void)n_in; (void)out_size; (void)ws_size;
  const int* src = (const int*)d_in[0];
  const int* trg = (const int*)d_in[1];
  const float* enc_emb = (const float*)d_in[3];
  const float* dec_emb = (const float*)d_in[4];
  const float* enc_Wih = (const float*)d_in[5];
  const float* enc_Whh = (const float*)d_in[6];
  const float* enc_bih = (const float*)d_in[7];
  const float* enc_bhh = (const float*)d_in[8];
  const float* dec_Wih = (const float*)d_in[9];
  const float* dec_Whh = (const float*)d_in[10];
  const float* dec_bih = (const float*)d_in[11];
  const float* dec_bhh = (const float*)d_in[12];
  const float* out_W = (const float*)d_in[13];
  const float* out_b = (const float*)d_in[14];

  char* p = (char*)d_ws;
  auto alloc = [&](size_t sz) { char* r = p; p += (sz + 255) & ~(size_t)255; return r; };
  short* H1 = (short*)alloc((size_t)257 * SLOT * 2);       // 16.84 MB
  short* H0r = (short*)alloc((size_t)2 * SLOT * 2);        // 128 KB ring
  short* W0e = (short*)alloc((size_t)2048 * 1024 * 2);     // 4 MB each
  short* W0d = (short*)alloc((size_t)2048 * 1024 * 2);
  short* W1e = (short*)alloc((size_t)2048 * 1024 * 2);
  short* W1d = (short*)alloc((size_t)2048 * 1024 * 2);
  short* outWb = (short*)alloc((size_t)16000 * 512 * 2);   // 15.63 MB
  short* X = (short*)alloc((size_t)16384 * 512 * 2);       // 16 MB
  float* bE0 = (float*)alloc(2048 * 4);
  float* bE1 = (float*)alloc(2048 * 4);
  float* bD0 = (float*)alloc(2048 * 4);
  float* bD1 = (float*)alloc(2048 * 4);
  unsigned* flags = (unsigned*)alloc(256);
  // total ~64.7 MB (<= 72 MB proven safe)

  // zero: h0 ring slot 0, h1 slot 0, h1 pad slot 256, flags
  zero_k<<<128, 256, 0, stream>>>(H0r, 32768);
  zero_k<<<128, 256, 0, stream>>>(H1, 32768);
  zero_k<<<128, 256, 0, stream>>>(H1 + (size_t)256 * SLOT, 32768);
  zero_k<<<1, 256, 0, stream>>>((short*)flags, 128);

  // weight conversion / reorder: [Wih | Whh] concat, gate-interleaved rows
  conv_w<<<1024, 256, 0, stream>>>(enc_Wih, W0e, 2048, 1024, 0, 1);
  conv_w<<<1024, 256, 0, stream>>>(enc_Whh, W0e, 2048, 1024, 512, 1);
  conv_w<<<1024, 256, 0, stream>>>(dec_Wih, W0d, 2048, 1024, 0, 1);
  conv_w<<<1024, 256, 0, stream>>>(dec_Whh, W0d, 2048, 1024, 512, 1);
  conv_w<<<1024, 256, 0, stream>>>(enc_Wih + (size_t)2048 * 512, W1e, 2048, 1024, 0, 1);
  conv_w<<<1024, 256, 0, stream>>>(enc_Whh + (size_t)2048 * 512, W1e, 2048, 1024, 512, 1);
  conv_w<<<1024, 256, 0, stream>>>(dec_Wih + (size_t)2048 * 512, W1d, 2048, 1024, 0, 1);
  conv_w<<<1024, 256, 0, stream>>>(dec_Whh + (size_t)2048 * 512, W1d, 2048, 1024, 512, 1);
  conv_w<<<8000, 256, 0, stream>>>(out_W, outWb, 16000, 512, 0, 0);
  conv_b<<<8, 256, 0, stream>>>(enc_bih, enc_bhh, bE0);
  conv_b<<<8, 256, 0, stream>>>(enc_bih + 2048, enc_bhh + 2048, bE1);
  conv_b<<<8, 256, 0, stream>>>(dec_bih, dec_bhh, bD0);
  conv_b<<<8, 256, 0, stream>>>(dec_bih + 2048, dec_bhh + 2048, bD1);

  // embeddings: enc -> X slots 0..127, dec -> X slots 128..254 (pad zeroed)
  embed_k<<<8192, 256, 0, stream>>>(src, enc_emb, X, 8192);
  embed_k<<<8192, 256, 0, stream>>>(trg, dec_emb, X + (size_t)8192 * 512, 8128);

  // fused encoder+decoder recurrence (lockstep)
  PipeArgs pa = {W0e, W0d, W1e, W1d, X, bE0, bD0, bE1, bD1,
                 H0r, H1, flags, 128, 255};
  lstm_pipe<<<64, 256, 0, stream>>>(pa);

  // logits = H1 slots 129..255 (+pad) @ out_W^T + out_b -> fp32 d_out
  gemm_bt<<<dim3(125, 64), 256, 0, stream>>>(H1 + (size_t)129 * SLOT, outWb, out_b,
                                             (float*)d_out, 8128, 16000, 512, 16000,
                                             GF_BIAS | GF_GUARDM);
}

// Round 9
// 2373.190 us; speedup vs baseline: 1.3419x; 1.3419x over previous
//
#include <hip/hip_runtime.h>

// V=16000 E=512 H=512 L=2 S=128 T=128 B=64; gate dim 4H=2048
// Fused recurrence, per-layer dataflow sync, WRITE-ONCE histories:
//  - L0 (WGs 0..31): step t computes [X[t] | h0(t)] @ W0^T; publishes h0
//    state t+1 to H0[t+1] (256 slots, each address written once per run).
//    Waits only on its own done0[t]. Free-runs the whole sequence.
//  - L1 (WGs 32..63): step t computes [y0(t)=h0(t+1) | h1(t)] @ W1^T;
//    waits done0[t+1] (producer) and done1[t] (own); publishes H1[t+1]
//    (257 slots; 129..255 feed the logits GEMM; slot 256 zero pad).
// Coherence: publishes = sc1 write-through stores + vmcnt(0) + relaxed agent
// atomic arrive; fresh reads = sc1 loads. Since every exchanged address is
// written exactly once per run, no stale-clean-line hazard exists even if
// sc1 loads can hit local L2 (values across graph replays are identical).
// No buffer_inv anywhere: X/weights stay L2-resident.
// Loads are batched inline-asm (16 x 16B per phase -> one latency), then
// vmcnt(0) + sched_barrier(0) before the MFMAs (guide rule #18).
// WS ~67 MB (<=72 MB proven safe); outWb conversion runs AFTER the pipe and
// reuses X's region (stream-ordered, X dead by then).

typedef __attribute__((ext_vector_type(8))) short v8s;
typedef __attribute__((ext_vector_type(4))) short v4s;
typedef __attribute__((ext_vector_type(8))) _Float16 v8h;
typedef __attribute__((ext_vector_type(4))) float v4f;
typedef __attribute__((ext_vector_type(4))) unsigned int v4u;

#define AS1 __attribute__((address_space(1)))
#define AS3 __attribute__((address_space(3)))

__device__ __forceinline__ short f2h(float x) {
  _Float16 h = (_Float16)x;
  return __builtin_bit_cast(short, h);
}
__device__ __forceinline__ void gload16(const void* g, void* l) {
  __builtin_amdgcn_global_load_lds((const AS1 void*)g, (AS3 void*)l, 16, 0, 0);
}
__device__ __forceinline__ float sigf(float x) { return 1.f / (1.f + __expf(-x)); }
__device__ __forceinline__ float tanhfast(float x) { return 2.f / (1.f + __expf(-2.f * x)) - 1.f; }

__device__ __forceinline__ void ld16_sc1(v4u& d, const void* p) {
  asm volatile("global_load_dwordx4 %0, %1, off sc1" : "=v"(d) : "v"(p) : "memory");
}
__device__ __forceinline__ void ld16(v4u& d, const void* p) {
  asm volatile("global_load_dwordx4 %0, %1, off" : "=v"(d) : "v"(p));
}
__device__ __forceinline__ void spin_ge(unsigned* p, unsigned tgt) {
  while (__hip_atomic_load(p, __ATOMIC_RELAXED, __HIP_MEMORY_SCOPE_AGENT) < tgt)
    __builtin_amdgcn_s_sleep(1);
}

// ---------- weight convert fp32->fp16 + gate reorder (i,f,g,o interleave per unit)
__global__ void conv_w(const float* __restrict__ in, short* __restrict__ out,
                       int rows, int ldo, int coloff, int reorder) {
  int i = blockIdx.x * 256 + threadIdx.x;       // one float4 per thread
  if (i >= rows * 128) return;                  // K=512 -> 128 quads per row
  int r = i >> 7, k4 = (i & 127) * 4;
  int rr = reorder ? ((r & 511) * 4 + (r >> 9)) : r;
  float4 v = *(const float4*)(in + (size_t)r * 512 + k4);
  v4s s; s[0] = f2h(v.x); s[1] = f2h(v.y); s[2] = f2h(v.z); s[3] = f2h(v.w);
  *(v4s*)(out + (size_t)rr * ldo + coloff + k4) = s;
}

__global__ void conv_b(const float* __restrict__ a, const float* __restrict__ b,
                       float* __restrict__ o) {
  int r = blockIdx.x * 256 + threadIdx.x;
  if (r < 2048) o[(r & 511) * 4 + (r >> 9)] = a[r] + b[r];
}

// ---------- embedding gather to fp16
__global__ void embed_k(const int* __restrict__ ids, const float* __restrict__ emb,
                        short* __restrict__ out, int nvalid) {
  int row = blockIdx.x;
  int e = threadIdx.x * 2;
  float2 v = make_float2(0.f, 0.f);
  if (row < nvalid) {
    int id = ids[row];
    v = *(const float2*)(emb + (size_t)id * 512 + e);
  }
  unsigned pack = ((unsigned)(unsigned short)f2h(v.y) << 16) | (unsigned short)f2h(v.x);
  *(unsigned*)(out + (size_t)row * 512 + e) = pack;
}

__global__ void zero_k(short* p, int n) {
  int i = blockIdx.x * 256 + threadIdx.x;
  if (i < n) p[i] = 0;
}

// ---------- GEMM: C[M,N] = A[M,K] * B[N,K]^T (+bias), 128x128 tile, BK=64, fp16
#define GF_BIAS 2
#define GF_GUARDM 4

__global__ __launch_bounds__(256, 2) void gemm_bt(
    const short* __restrict__ Am, const short* __restrict__ Bm,
    const float* __restrict__ bias, float* __restrict__ Cm,
    int M, int N, int K, int ldc, int flags) {
  __shared__ short lA[128 * 64];
  __shared__ short lB[128 * 64];
  const int tid = threadIdx.x, lane = tid & 63, wave = tid >> 6;
  const int wm = wave >> 1, wn = wave & 1;
  const int tm = blockIdx.y, tn = blockIdx.x;
  v4f acc[4][4] = {};
  const short* Abase = Am + (size_t)tm * 128 * K;
  const short* Bbase = Bm + (size_t)tn * 128 * K;

  for (int kt = 0; kt < K; kt += 64) {
    __syncthreads();
#pragma unroll
    for (int i2 = 0; i2 < 4; ++i2) {
      int c = (wave * 4 + i2) * 64 + lane;    // 16B chunk id, 1024 per tile
      int row = c >> 3, ch = c & 7;
      int sch = ch ^ (row & 7);               // inverse swizzle on global source
      gload16(Abase + (size_t)row * K + kt + sch * 8, (char*)lA + (wave * 4 + i2) * 1024);
      gload16(Bbase + (size_t)row * K + kt + sch * 8, (char*)lB + (wave * 4 + i2) * 1024);
    }
    asm volatile("s_waitcnt vmcnt(0)" ::: "memory");
    __syncthreads();
#pragma unroll
    for (int kc = 0; kc < 2; ++kc) {
      v8h af[4], bh[4];
#pragma unroll
      for (int mt = 0; mt < 4; ++mt) {
        int row = wm * 64 + mt * 16 + (lane & 15);
        af[mt] = *(const v8h*)((const char*)lA + row * 128 +
                               ((kc * 64 + (lane >> 4) * 16) ^ ((row & 7) << 4)));
      }
#pragma unroll
      for (int nt = 0; nt < 4; ++nt) {
        int row = wn * 64 + nt * 16 + (lane & 15);
        bh[nt] = *(const v8h*)((const char*)lB + row * 128 +
                               ((kc * 64 + (lane >> 4) * 16) ^ ((row & 7) << 4)));
      }
#pragma unroll
      for (int mt = 0; mt < 4; ++mt)
#pragma unroll
        for (int nt = 0; nt < 4; ++nt)
          acc[mt][nt] = __builtin_amdgcn_mfma_f32_16x16x32_f16(af[mt], bh[nt], acc[mt][nt], 0, 0, 0);
    }
  }

  const int rbase = tm * 128 + wm * 64 + (lane >> 4) * 4;
  const int cbase = tn * 128 + wn * 64 + (lane & 15);
#pragma unroll
  for (int mt = 0; mt < 4; ++mt) {
#pragma unroll
    for (int nt = 0; nt < 4; ++nt) {
      int gc = cbase + nt * 16;
      float bv = (flags & GF_BIAS) ? bias[gc] : 0.f;
#pragma unroll
      for (int rg = 0; rg < 4; ++rg) {
        int gr = rbase + mt * 16 + rg;
        if ((flags & GF_GUARDM) && gr >= M) continue;
        Cm[(size_t)gr * ldc + gc] = acc[mt][nt][rg] + bv;
      }
    }
  }
}

// ---------- fused 2-layer enc+dec LSTM, per-layer dataflow, write-once histories
struct PipeArgs {
  const short* W0e;  // [2048][1024] fp16 [Wih|Whh] gate-reordered
  const short* W0d;
  const short* W1e;
  const short* W1d;
  const short* X;    // [255][64][512] fp16 embeddings (slot t = x_t)
  const float* b0e;  // [2048] fp32 reordered biases
  const float* b0d;
  const float* b1e;
  const float* b1d;
  short* h0;         // 256 slots: state s at slot s (write-once)
  short* h1;         // 257 slots: state s at slot s (write-once)
  unsigned* done0;   // [256] counters, stride 32 uints; ==32 <=> state published
  unsigned* done1;
  int Tenc, Ttot;    // 128, 255
};

#define PRE_LD 68
#define SLOT 32768

__global__ __launch_bounds__(256, 1) void lstm_pipe(PipeArgs A) {
  __shared__ __align__(16) short Wlds[64 * 1024];   // 128 KB
  __shared__ __align__(16) float pre[64 * PRE_LD];  // 17 KB
  __shared__ __align__(16) short hsm[64 * 16];      // 2 KB
  const int tid = threadIdx.x, lane = tid & 63, wave = tid >> 6;
  const int w = blockIdx.x, layer = w >> 5, wl = w & 31;

  auto stage = [&](const short* Wsrc) {
    for (int i = tid * 8; i < 64 * 1024; i += 256 * 8) {
      int row = i >> 10, k = i & 1023;
      v8s v = *(const v8s*)(Wsrc + (size_t)row * 1024 + k);
      *(v8s*)((char*)Wlds + row * 2048 + ((k * 2) ^ ((row & 7) << 4))) = v;
    }
  };
  stage(((layer ? A.W1e : A.W0e)) + (size_t)(wl * 64) * 1024);

  const int uu = tid & 15, bq0 = tid >> 4;
  const float* bpe = (layer ? A.b1e : A.b0e) + wl * 64 + uu * 4;
  const float* bpd = (layer ? A.b1d : A.b0d) + wl * 64 + uu * 4;
  const float be0 = bpe[0], be1 = bpe[1], be2 = bpe[2], be3 = bpe[3];
  const float bd0 = bpd[0], bd1 = bpd[1], bd2 = bpd[2], bd3 = bpd[3];
  float creg[4] = {0.f, 0.f, 0.f, 0.f};
  unsigned* own = layer ? A.done1 : A.done0;

  const int arow = wave * 16 + (lane & 15);
  const int koff = (lane >> 4) * 8;
  __syncthreads();

  for (int t = 0; t < A.Ttot; ++t) {
    if (t == A.Tenc) {                    // per-layer decoder weight switch
      stage((layer ? A.W1d : A.W0d) + (size_t)(wl * 64) * 1024);
      __syncthreads();
    }

    // ---- phase 1: input half. L0: X[t] (static). L1: y0(t)=h0 state t+1.
    if (layer) {
      if (tid == 0) spin_ge(A.done0 + (size_t)(t + 1) * 32, 32u);
      __syncthreads();
    }
    const short* s1 = layer ? (A.h0 + (size_t)(t + 1) * SLOT)
                            : (A.X + (size_t)t * SLOT);
    const short* p1 = s1 + (size_t)arow * 512 + koff;
    v4u fa[16];
    if (layer) {
#pragma unroll
      for (int kc = 0; kc < 16; ++kc) ld16_sc1(fa[kc], p1 + kc * 32);
    } else {
#pragma unroll
      for (int kc = 0; kc < 16; ++kc) ld16(fa[kc], p1 + kc * 32);
    }
    asm volatile("s_waitcnt vmcnt(0)" ::: "memory");
    __builtin_amdgcn_sched_barrier(0);
    v4f acc[4] = {};
#pragma unroll
    for (int kc = 0; kc < 16; ++kc) {
      v8h af = __builtin_bit_cast(v8h, fa[kc]);
      int kg = kc * 32 + koff;
#pragma unroll
      for (int nt = 0; nt < 4; ++nt) {
        int wrow = nt * 16 + (lane & 15);
        v8h bh = *(const v8h*)((const char*)Wlds + wrow * 2048 +
                               ((kg * 2) ^ ((wrow & 7) << 4)));
        acc[nt] = __builtin_amdgcn_mfma_f32_16x16x32_f16(af, bh, acc[nt], 0, 0, 0);
      }
    }

    // ---- phase 2: recurrent half (own h state t)
    if (tid == 0 && t > 0) spin_ge(own + (size_t)t * 32, 32u);
    __syncthreads();
    const short* s2 = (layer ? A.h1 : A.h0) + (size_t)t * SLOT;
    const short* p2 = s2 + (size_t)arow * 512 + koff;
    v4u fb[16];
#pragma unroll
    for (int kc = 0; kc < 16; ++kc) ld16_sc1(fb[kc], p2 + kc * 32);
    asm volatile("s_waitcnt vmcnt(0)" ::: "memory");
    __builtin_amdgcn_sched_barrier(0);
#pragma unroll
    for (int kc = 0; kc < 16; ++kc) {
      v8h af = __builtin_bit_cast(v8h, fb[kc]);
      int kg = (kc + 16) * 32 + koff;
#pragma unroll
      for (int nt = 0; nt < 4; ++nt) {
        int wrow = nt * 16 + (lane & 15);
        v8h bh = *(const v8h*)((const char*)Wlds + wrow * 2048 +
                               ((kg * 2) ^ ((wrow & 7) << 4)));
        acc[nt] = __builtin_amdgcn_mfma_f32_16x16x32_f16(af, bh, acc[nt], 0, 0, 0);
      }
    }
#pragma unroll
    for (int nt = 0; nt < 4; ++nt)
#pragma unroll
      for (int rg = 0; rg < 4; ++rg)
        pre[(wave * 16 + (lane >> 4) * 4 + rg) * PRE_LD + nt * 16 + (lane & 15)] = acc[nt][rg];
    __syncthreads();

    // activations + cell update; h into LDS staging
    {
      const bool enc = t < A.Tenc;
#pragma unroll
      for (int q = 0; q < 4; ++q) {
        int b = q * 16 + bq0;
        v4f gv = *(const v4f*)(&pre[b * PRE_LD + uu * 4]);
        float g0 = gv[0] + (enc ? be0 : bd0);
        float g1 = gv[1] + (enc ? be1 : bd1);
        float g2 = gv[2] + (enc ? be2 : bd2);
        float g3 = gv[3] + (enc ? be3 : bd3);
        float c = sigf(g1) * creg[q] + sigf(g0) * tanhfast(g2);
        creg[q] = c;
        float h = sigf(g3) * tanhfast(c);
        hsm[b * 16 + uu] = f2h(h);
      }
    }
    __syncthreads();

    // publish state t+1 (write-once address): sc1 stores, drain, arrive
    if (tid < 128) {
      int b = tid >> 1, half = tid & 1;
      v4u d = *(const v4u*)(&hsm[b * 16 + half * 8]);
      short* dst = (layer ? A.h1 : A.h0) + (size_t)(t + 1) * SLOT
                   + b * 512 + wl * 16 + half * 8;
      asm volatile("global_store_dwordx4 %0, %1, off sc1" :: "v"(dst), "v"(d) : "memory");
    }
    asm volatile("s_waitcnt vmcnt(0)" ::: "memory");
    __syncthreads();
    if (tid == 0)
      __hip_atomic_fetch_add(own + (size_t)(t + 1) * 32, 1u,
                             __ATOMIC_RELAXED, __HIP_MEMORY_SCOPE_AGENT);
  }
}

extern "C" void kernel_launch(void* const* d_in, const int* in_sizes, int n_in,
                              void* d_out, int out_size, void* d_ws, size_t ws_size,
                              hipStream_t stream) {
  (void)in_sizes; (void)n_in; (void)out_size; (void)ws_size;
  const int* src = (const int*)d_in[0];
  const int* trg = (const int*)d_in[1];
  const float* enc_emb = (const float*)d_in[3];
  const float* dec_emb = (const float*)d_in[4];
  const float* enc_Wih = (const float*)d_in[5];
  const float* enc_Whh = (const float*)d_in[6];
  const float* enc_bih = (const float*)d_in[7];
  const float* enc_bhh = (const float*)d_in[8];
  const float* dec_Wih = (const float*)d_in[9];
  const float* dec_Whh = (const float*)d_in[10];
  const float* dec_bih = (const float*)d_in[11];
  const float* dec_bhh = (const float*)d_in[12];
  const float* out_W = (const float*)d_in[13];
  const float* out_b = (const float*)d_in[14];

  char* p = (char*)d_ws;
  auto alloc = [&](size_t sz) { char* r = p; p += (sz + 255) & ~(size_t)255; return r; };
  short* H0 = (short*)alloc((size_t)256 * SLOT * 2);       // 16.78 MB, write-once
  short* H1 = (short*)alloc((size_t)257 * SLOT * 2);       // 16.84 MB, write-once
  short* W0e = (short*)alloc((size_t)2048 * 1024 * 2);     // 4 MB each
  short* W0d = (short*)alloc((size_t)2048 * 1024 * 2);
  short* W1e = (short*)alloc((size_t)2048 * 1024 * 2);
  short* W1d = (short*)alloc((size_t)2048 * 1024 * 2);
  short* XO = (short*)alloc((size_t)255 * SLOT * 2);       // 16.71 MB: X, then outWb
  float* bE0 = (float*)alloc(2048 * 4);
  float* bE1 = (float*)alloc(2048 * 4);
  float* bD0 = (float*)alloc(2048 * 4);
  float* bD1 = (float*)alloc(2048 * 4);
  unsigned* done0 = (unsigned*)alloc(256 * 32 * 4);        // 32 KB each
  unsigned* done1 = (unsigned*)alloc(256 * 32 * 4);
  // total ~67 MB (<= 72 MB proven safe)

  // zero: h0 state 0, h1 state 0, h1 pad slot 256, done counters (64 KB)
  zero_k<<<128, 256, 0, stream>>>(H0, 32768);
  zero_k<<<128, 256, 0, stream>>>(H1, 32768);
  zero_k<<<128, 256, 0, stream>>>(H1 + (size_t)256 * SLOT, 32768);
  zero_k<<<128, 256, 0, stream>>>((short*)done0, 32768);

  // weight conversion / reorder: [Wih | Whh] concat, gate-interleaved rows
  conv_w<<<1024, 256, 0, stream>>>(enc_Wih, W0e, 2048, 1024, 0, 1);
  conv_w<<<1024, 256, 0, stream>>>(enc_Whh, W0e, 2048, 1024, 512, 1);
  conv_w<<<1024, 256, 0, stream>>>(dec_Wih, W0d, 2048, 1024, 0, 1);
  conv_w<<<1024, 256, 0, stream>>>(dec_Whh, W0d, 2048, 1024, 512, 1);
  conv_w<<<1024, 256, 0, stream>>>(enc_Wih + (size_t)2048 * 512, W1e, 2048, 1024, 0, 1);
  conv_w<<<1024, 256, 0, stream>>>(enc_Whh + (size_t)2048 * 512, W1e, 2048, 1024, 512, 1);
  conv_w<<<1024, 256, 0, stream>>>(dec_Wih + (size_t)2048 * 512, W1d, 2048, 1024, 0, 1);
  conv_w<<<1024, 256, 0, stream>>>(dec_Whh + (size_t)2048 * 512, W1d, 2048, 1024, 512, 1);
  conv_b<<<8, 256, 0, stream>>>(enc_bih, enc_bhh, bE0);
  conv_b<<<8, 256, 0, stream>>>(enc_bih + 2048, enc_bhh + 2048, bE1);
  conv_b<<<8, 256, 0, stream>>>(dec_bih, dec_bhh, bD0);
  conv_b<<<8, 256, 0, stream>>>(dec_bih + 2048, dec_bhh + 2048, bD1);

  // embeddings: enc -> X slots 0..127, dec -> slots 128..254 (8128 rows exactly)
  embed_k<<<8192, 256, 0, stream>>>(src, enc_emb, XO, 8192);
  embed_k<<<8128, 256, 0, stream>>>(trg, dec_emb, XO + (size_t)8192 * 512, 8128);

  // fused encoder+decoder recurrence (per-layer dataflow, write-once)
  PipeArgs pa = {W0e, W0d, W1e, W1d, XO, bE0, bD0, bE1, bD1,
                 H0, H1, done0, done1, 128, 255};
  lstm_pipe<<<64, 256, 0, stream>>>(pa);

  // outWb conversion reuses X's region (X dead after the pipe; stream-ordered)
  short* outWb = XO;
  conv_w<<<8000, 256, 0, stream>>>(out_W, outWb, 16000, 512, 0, 0);

  // logits = H1 slots 129..255 (+pad) @ out_W^T + out_b -> fp32 d_out
  gemm_bt<<<dim3(125, 64), 256, 0, stream>>>(H1 + (size_t)129 * SLOT, outWb, out_b,
                                             (float*)d_out, 8128, 16000, 512, 16000,
                                             GF_BIAS | GF_GUARDM);
}